// Round 17
// baseline (27.779 us; speedup 1.0000x reference)
//
#include <hip/hip_runtime.h>
#include <hip/hip_fp16.h>
#include <math.h>

#define NROWS 2048
#define DDIM 32

typedef __attribute__((ext_vector_type(8))) short short8;  // 8 bf16
typedef __attribute__((ext_vector_type(4))) float f32x4;

union H8 {
  _Float16 h[8];
  uint4 u;
};

__device__ __forceinline__ unsigned packbf(float a, float b) {
  // bf16(a) in low 16, bf16(b) in high 16 (truncation; lo-plane captures rest)
  return (__float_as_uint(a) >> 16) | (__float_as_uint(b) & 0xffff0000u);
}

// ---------------------------------------------------------------------------
// Single fused kernel. 128x128 tile per 512-thread block (8 waves, 2/SIMD).
// r14 structure, but cos/sin stored as fp16 (arithmetic stays f32 via
// v_fma_mix): one b128 LDS read now carries 4 d's -> quantum has 8 phases of
// 12 reads (was 16), halving the binding LDS-pipe cost.
//   sCSh[side][q*128 + (row ^ q)] : uint4 = 8 fp16 (hc0,hs0,...,hc3,hs3),
//   q = d-quad 0..7. x side folds ALPHA=0.5 into hc/hs.
// Order: tile loads -> cs staging -> stats stream (redundant per block,
//   L2-resident) -> reduce -> bf16 hi/lo staging -> MFMA classical ->
//   quantum (fp16 operands, f32 math) -> combine -> store.
// classical = exp(2*dot - nx - ny); quantum term = 0.5 + hcx*cy + hsx*sy.
// ---------------------------------------------------------------------------
__global__ __launch_bounds__(512, 2) void HybridKernel_fused(
    const float* __restrict__ x, const float* __restrict__ y,
    float* __restrict__ out) {
  __shared__ uint4 sCSh[2][8 * 128];    // 32 KB fp16 cos/sin quads
  __shared__ uint4 sXB[2][2][128 * 5];  // 40 KB bf16 [side][hi/lo], 80B/row
  __shared__ f32x4 sRed[2][64][8];      // 16 KB stats partials (sum)
  __shared__ f32x4 sRedQ[2][64][8];     // 16 KB stats partials (sumsq)
  __shared__ float sNrm[2][128];
  __shared__ float sMu[2][32];
  __shared__ float sInv[2][32];

  const int t = threadIdx.x;
  const int i0 = blockIdx.y * 128;
  const int j0 = blockIdx.x * 128;

  // --- 1. hoist tile global loads ---
  float4 gx[2], gy[2];
#pragma unroll
  for (int rep = 0; rep < 2; ++rep) {
    const int u = t + 512 * rep;
    const int row = u >> 3;
    const int q = u & 7;
    gx[rep] = *reinterpret_cast<const float4*>(&x[(i0 + row) * DDIM + q * 4]);
    gy[rep] = *reinterpret_cast<const float4*>(&y[(j0 + row) * DDIM + q * 4]);
  }

  // --- 2. cs staging (fp16 pack, 4 d's per slot) ---
#pragma unroll
  for (int rep = 0; rep < 2; ++rep) {
    const int u = t + 512 * rep;
    const int row = u >> 3;
    const int q = u & 7;
#pragma unroll
    for (int side = 0; side < 2; ++side) {
      const float4 g = side ? gy[rep] : gx[rep];
      const float sc = side ? 1.0f : 0.5f;
      const float gv[4] = {g.x, g.y, g.z, g.w};
      H8 pk;
#pragma unroll
      for (int k = 0; k < 4; ++k) {
        float sn, cs;
        __sincosf(gv[k], &sn, &cs);
        pk.h[2 * k] = (_Float16)(sc * cs);
        pk.h[2 * k + 1] = (_Float16)(sc * sn);
      }
      sCSh[side][q * 128 + (row ^ q)] = pk.u;
    }
  }

  // --- 3. stats streaming ---
  {
    const int cq = t & 7;
    const int rg = t >> 3;  // 0..63
    const f32x4* px = reinterpret_cast<const f32x4*>(x) + rg * 8 + cq;
    const f32x4* py = reinterpret_cast<const f32x4*>(y) + rg * 8 + cq;
    f32x4 sx = {0.f, 0.f, 0.f, 0.f}, qx = {0.f, 0.f, 0.f, 0.f};
    f32x4 sy = {0.f, 0.f, 0.f, 0.f}, qy = {0.f, 0.f, 0.f, 0.f};
#pragma unroll 4
    for (int i = 0; i < NROWS / 64; ++i) {  // 32 iters
      const f32x4 vx = px[(size_t)i * 64 * 8];
      const f32x4 vy = py[(size_t)i * 64 * 8];
      sx += vx;
      qx = __builtin_elementwise_fma(vx, vx, qx);
      sy += vy;
      qy = __builtin_elementwise_fma(vy, vy, qy);
    }
    sRed[0][rg][cq] = sx;
    sRedQ[0][rg][cq] = qx;
    sRed[1][rg][cq] = sy;
    sRedQ[1][rg][cq] = qy;
  }
  __syncthreads();
  if (t < 128) {
    const int a = t >> 6;
    const int g8 = (t >> 3) & 7;
    const int cq2 = t & 7;
    f32x4 S = {0.f, 0.f, 0.f, 0.f}, Q = {0.f, 0.f, 0.f, 0.f};
#pragma unroll
    for (int k = 0; k < 8; ++k) {
      S += sRed[a][g8 * 8 + k][cq2];
      Q += sRedQ[a][g8 * 8 + k][cq2];
    }
    sRed[a][g8][cq2] = S;
    sRedQ[a][g8][cq2] = Q;
  }
  __syncthreads();
  if (t < 16) {  // t = a*8 + cq
    const int a = t >> 3;
    const int cq2 = t & 7;
    f32x4 S = {0.f, 0.f, 0.f, 0.f}, Q = {0.f, 0.f, 0.f, 0.f};
#pragma unroll
    for (int k = 0; k < 8; ++k) {
      S += sRed[a][k][cq2];
      Q += sRedQ[a][k][cq2];
    }
    const float n = (float)NROWS;
#pragma unroll
    for (int k = 0; k < 4; ++k) {
      const float mean = S[k] / n;
      const float var = fmaxf((Q[k] - S[k] * mean) / (n - 1.f), 0.f);
      sMu[a][cq2 * 4 + k] = mean;
      sInv[a][cq2 * 4 + k] = 1.f / (sqrtf(var) + 1e-8f);
    }
  }
  __syncthreads();

  // --- 4. bf16 hi/lo staging + row norms ---
#pragma unroll
  for (int rep = 0; rep < 2; ++rep) {
    const int u = t + 512 * rep;
    const int row = u >> 3;
    const int q = u & 7;
#pragma unroll
    for (int side = 0; side < 2; ++side) {
      const float4 g = side ? gy[rep] : gx[rep];
      const float gv[4] = {g.x, g.y, g.z, g.w};
      float xn[4];
      float nrm = 0.f;
#pragma unroll
      for (int k = 0; k < 4; ++k) {
        const int d = q * 4 + k;
        xn[k] = (gv[k] - sMu[side][d]) * sInv[side][d];
        nrm = fmaf(xn[k], xn[k], nrm);
      }
      float hif[4], lof[4];
#pragma unroll
      for (int k = 0; k < 4; ++k) {
        hif[k] = __uint_as_float(__float_as_uint(xn[k]) & 0xffff0000u);
        lof[k] = xn[k] - hif[k];
      }
      char* bh = (char*)&sXB[side][0][0] + row * 80 + q * 8;
      char* bl = (char*)&sXB[side][1][0] + row * 80 + q * 8;
      *reinterpret_cast<uint2*>(bh) =
          make_uint2(packbf(hif[0], hif[1]), packbf(hif[2], hif[3]));
      *reinterpret_cast<uint2*>(bl) =
          make_uint2(packbf(lof[0], lof[1]), packbf(lof[2], lof[3]));
      nrm += __shfl_xor(nrm, 1);
      nrm += __shfl_xor(nrm, 2);
      nrm += __shfl_xor(nrm, 4);
      if ((t & 7) == 0) sNrm[side][row] = nrm;
    }
  }
  __syncthreads();

  // --- wave/lane geometry (MFMA C/D layout) ---
  const int w = t >> 6;
  const int l = t & 63;
  const int l4 = l >> 4;  // 0..3
  const int ln = l & 15;
  const int R0 = (w >> 1) * 32;  // wave row base
  const int C0 = (w & 1) * 64;   // wave col base

  int r_idx[8], c_idx[4];
#pragma unroll
  for (int ri = 0; ri < 8; ++ri)
    r_idx[ri] = R0 + 16 * (ri >> 2) + 4 * l4 + (ri & 3);
#pragma unroll
  for (int tc = 0; tc < 4; ++tc) c_idx[tc] = C0 + 16 * tc + ln;

  // --- 5. classical via MFMA: 2x4 tiles, hi/lo 3-pass ---
  short8 Ah[2], Al[2], Bh[4], Bl[4];
  {
    const char* bxh = (const char*)&sXB[0][0][0];
    const char* bxl = (const char*)&sXB[0][1][0];
    const char* byh = (const char*)&sXB[1][0][0];
    const char* byl = (const char*)&sXB[1][1][0];
#pragma unroll
    for (int tr = 0; tr < 2; ++tr) {
      const int off = (R0 + 16 * tr + ln) * 80 + l4 * 16;
      Ah[tr] = *reinterpret_cast<const short8*>(bxh + off);
      Al[tr] = *reinterpret_cast<const short8*>(bxl + off);
    }
#pragma unroll
    for (int tc = 0; tc < 4; ++tc) {
      const int off = (C0 + 16 * tc + ln) * 80 + l4 * 16;
      Bh[tc] = *reinterpret_cast<const short8*>(byh + off);
      Bl[tc] = *reinterpret_cast<const short8*>(byl + off);
    }
  }
  f32x4 dotacc[2][4];
#pragma unroll
  for (int tr = 0; tr < 2; ++tr)
#pragma unroll
    for (int tc = 0; tc < 4; ++tc) {
      f32x4 a = {0.f, 0.f, 0.f, 0.f};
      a = __builtin_amdgcn_mfma_f32_16x16x32_bf16(Ah[tr], Bl[tc], a, 0, 0, 0);
      a = __builtin_amdgcn_mfma_f32_16x16x32_bf16(Al[tr], Bh[tc], a, 0, 0, 0);
      a = __builtin_amdgcn_mfma_f32_16x16x32_bf16(Ah[tr], Bh[tc], a, 0, 0, 0);
      dotacc[tr][tc] = a;
    }

  // --- 6. quantum: 8 phases, fp16 operands, f32 math (v_fma_mix) ---
  const uint4* sCS0 = &sCSh[0][0];
  const uint4* sCS1 = &sCSh[1][0];
  float qp[8][4];
#pragma unroll
  for (int ri = 0; ri < 8; ++ri)
#pragma unroll
    for (int tc = 0; tc < 4; ++tc) qp[ri][tc] = 1.f;

#pragma unroll
  for (int q = 0; q < 8; ++q) {
    const int base = q * 128;
    H8 fy[4];
#pragma unroll
    for (int tc = 0; tc < 4; ++tc) fy[tc].u = sCS1[base + (c_idx[tc] ^ q)];
#pragma unroll
    for (int ri = 0; ri < 8; ++ri) {
      H8 fx;
      fx.u = sCS0[base + (r_idx[ri] ^ q)];
#pragma unroll
      for (int tc = 0; tc < 4; ++tc) {
        const float t0 = fmaf((float)fx.h[0], (float)fy[tc].h[0],
                              fmaf((float)fx.h[1], (float)fy[tc].h[1], 0.5f));
        const float t1 = fmaf((float)fx.h[2], (float)fy[tc].h[2],
                              fmaf((float)fx.h[3], (float)fy[tc].h[3], 0.5f));
        const float t2 = fmaf((float)fx.h[4], (float)fy[tc].h[4],
                              fmaf((float)fx.h[5], (float)fy[tc].h[5], 0.5f));
        const float t3 = fmaf((float)fx.h[6], (float)fy[tc].h[6],
                              fmaf((float)fx.h[7], (float)fy[tc].h[7], 0.5f));
        qp[ri][tc] *= (t0 * t1) * (t2 * t3);
      }
    }
  }

  // --- 7. classical epilogue + combine + store ---
#pragma unroll
  for (int tr = 0; tr < 2; ++tr) {
#pragma unroll
    for (int mm = 0; mm < 4; ++mm) {
      const int ri = tr * 4 + mm;
      const float nx = sNrm[0][r_idx[ri]];
      float* o = out + (size_t)(i0 + r_idx[ri]) * NROWS + j0;
#pragma unroll
      for (int tc = 0; tc < 4; ++tc) {
        const float ny = sNrm[1][c_idx[tc]];
        const float cl = __expf(2.f * dotacc[tr][tc][mm] - nx - ny);
        o[c_idx[tc]] = 0.5f * (cl + qp[ri][tc]);
      }
    }
  }
}

extern "C" void kernel_launch(void* const* d_in, const int* in_sizes, int n_in,
                              void* d_out, int out_size, void* d_ws,
                              size_t ws_size, hipStream_t stream) {
  const float* x = (const float*)d_in[0];
  const float* y = (const float*)d_in[1];
  float* out = (float*)d_out;

  dim3 grid(NROWS / 128, NROWS / 128);
  HybridKernel_fused<<<grid, 512, 0, stream>>>(x, y, out);
}